// Round 12
// baseline (1013.365 us; speedup 1.0000x reference)
//
#include <hip/hip_runtime.h>
#include <hip/hip_bf16.h>
#include <hip/hip_fp16.h>
#include <math.h>

#define DEV static __device__ __forceinline__

DEV float siluf(float x){ return x / (1.f + expf(-x)); }
DEV float softplusf(float x){ return (x > 20.f) ? x : log1pf(__expf(x)); }

DEV unsigned short f2bf(float f){
  unsigned int u = __float_as_uint(f);
  unsigned int r = (u + 0x7FFFu + ((u >> 16) & 1u)) >> 16;
  return (unsigned short)r;
}

using bf16x8 = __attribute__((ext_vector_type(8))) short;
using u16x8  = __attribute__((ext_vector_type(8))) unsigned short;
using f32x4  = __attribute__((ext_vector_type(4))) float;

// ---------------- input arena offsets (floats) ----------------
constexpr long long I_LD=0, I_C0W=9216, I_C0B=10944, I_MINW=10976, I_MCONVW=1198816,
 I_MCONVB=1203936, I_MDTB=1205216, I_MALOG=1205232, I_MD=1205248, I_MNORMW=1205264,
 I_MOUTW=1206288, I_C1W=1730576, I_C1B=3303440, I_V1LNW=3304464, I_V1LNB=3304496,
 I_V1INW=3304528, I_V1CONVW=3308624, I_V1CONVB=3309200, I_V1XPW=3309264, I_V1DTW=3317968,
 I_V1DTB=3318480, I_V1ALOG=3318736, I_V1D=3322832, I_V1ONW=3323088, I_V1ONB=3323152,
 I_V1OUTW=3323216, I_DW1W=3325264, I_DW1B=3325552, I_PW1W=3325584, I_PW1B=3327632,
 I_DW2W=3327696, I_DW2B=3328272, I_PW2W=3328336, I_PW2B=3336528, I_CV1W=3336656,
 I_CV1B=3484112, I_CV2W=3484240, I_CV2B=3517008, I_FCW=3517264, I_FCB=4696912,
 I_V2LNW=4697424, I_V2LNB=4697936, I_V2INW=4698448, I_V2CONVW=5747024, I_V2CONVB=5756240,
 I_V2XPW=5757264, I_V2DTW=6019408, I_V2DTB=6150480, I_V2ALOG=6154576, I_V2D=6220112,
 I_V2ONW=6224208, I_V2ONB=6225232, I_V2OUTW=6226256;
constexpr long long TOTAL_IN = 6750544;
constexpr int INGEST_BLOCKS = (int)((TOTAL_IN + 255) / 256);
constexpr long long O_E8 = 6750544;                // (512,4096) f32, lives to the end
constexpr long long SCR  = 8847696;
// phase 1 (stages A-E)
constexpr long long O_X0=SCR+0, O_ZX=SCR+16384, O_XBCC=SCR+90624, O_DTM=SCR+131584,
 O_TPRE=SCR+132096, O_TG=SCR+164864, O_OUTM=SCR+197632, O_Y1=SCR+214016, O_H1=SCR+246784,
 O_XZ1=SCR+279552, O_XC1=SCR+410624, O_DBL1=SCR+476160, O_YS1=SCR+615424, O_G1=SCR+877568,
 O_OUTD=SCR+943104, O_E1=SCR+975872, O_E2=SCR+1008640, O_E3=SCR+1074176, O_E4=SCR+1139712,
 O_E5=SCR+1270784, O_E6=SCR+1795072, O_E7=SCR+2319360;
// vss1 scan scratch
constexpr long long O_XT1=SCR+3367936, O_P1=SCR+3433472, O_S1=SCR+3499008;   // S1 ends 3564544
// free gap 3564544..4000000
constexpr long long O_CV2WB=SCR+3564544;  // ends 3580928
constexpr long long O_CV1WB=SCR+3580928;  // ends 3654656
// fc/cv MFMA scratch (phase-1 tail)
constexpr long long O_FCW2=SCR+4000000;   // ends 4589824
constexpr long long O_E7T =SCR+4600000;   // ends 5124288
constexpr long long O_E6TB=O_E7T;
constexpr long long O_E5TB=O_E7T;
constexpr long long O_B2  =SCR+5242880;   // ends 9961472 (phase-1 only)
constexpr long long O_CV1B2=O_B2;
// phase 2 (stage F)
constexpr long long O_XZ2=SCR+0;                        // 4096x2048 f32 (z live till comb2)
constexpr long long O_XC2=SCR+8388608;                  // dwcs2 out f32 (dead after transpose_dual)
constexpr long long O_P2 =O_XC2;                        // overlay: P (64x65536=4194304, fits exactly)
constexpr long long O_XT2=SCR+12582912;                 // XP[ch][pix] f32 (dead after dwcs2)
constexpr long long O_G2 =O_XT2;                        // bf16 G2 (comb2 out)
constexpr long long O_DBL2=SCR+16777216;                // G[256][4096] f32 (live in scans)
constexpr long long O_S2 =SCR+17825792;                 // S (64x65536), ends 22020096
constexpr long long O_YS2=SCR+22020096;                 // fp16 ys (ends 30408704)
constexpr long long O_LN2=SCR+30408704;                 // bf16 LN2 (ends 31457280)
// bf16 weights / staging (top region, no overlap)
constexpr long long O_W2INB=SCR+32505856;               // ends 33030144
constexpr long long O_XPWB =SCR+33030144;               // ends 33161216
constexpr long long O_OUTWB=SCR+33161216;               // ends 33423360
constexpr long long O_XT2B =SCR+33423360;               // ends 35520512
constexpr long long WS_FLOATS = SCR + 36700160;

struct PtrTab { const void* p[53]; };

__constant__ long long c_inoff[53] = { 0, 9216, 10944, 10976, 1198816, 1203936, 1205216,
 1205232, 1205248, 1205264, 1206288, 1730576, 3303440, 3304464, 3304496, 3304528, 3308624,
 3309200, 3309264, 3317968, 3318480, 3318736, 3322832, 3323088, 3323152, 3323216, 3325264,
 3325552, 3325584, 3327632, 3327696, 3328272, 3328336, 3336528, 3336656, 3484112, 3484240,
 3517008, 3517264, 4696912, 4697424, 4697936, 4698448, 5747024, 5756240, 5757264, 6019408,
 6150480, 6154576, 6220112, 6224208, 6225232, 6226256 };

DEV int scan_addr(int k, int l, int lg, int Lm1){
  int p = (k & 2) ? (Lm1 - l) : l;
  int mask = (1 << lg) - 1;
  if (k & 1) p = ((p & mask) << lg) | (p >> lg);
  return p;
}

// =============== ingest ===============
__global__ void k_ingest(PtrTab t, float* __restrict__ W){
  long long idx = (long long)blockIdx.x*256 + threadIdx.x;
  if (idx >= TOTAL_IN) return;
  int j = 0;
  #pragma unroll
  for (int q=1; q<53; ++q) if (idx >= c_inoff[q]) j = q;
  int local = (int)(idx - c_inoff[j]);
  bool bf = (*(const unsigned int*)t.p[9]) == 0x3F803F80u;
  float v;
  if (bf){
    unsigned short u = ((const unsigned short*)t.p[j])[local];
    v = __uint_as_float(((unsigned int)u) << 16);
  } else {
    v = ((const float*)t.p[j])[local];
  }
  W[idx] = v;
}

// =============== merged weight prep ===============
__global__ void k_prep(float* __restrict__ W){
  long long i = (long long)blockIdx.x*256 + threadIdx.x;
  if (i < 1048576){
    ((unsigned short*)(W + O_W2INB))[i] = f2bf(W[I_V2INW + i]);
  } else if (i < 1310720){
    long long d = i - 1048576;
    ((unsigned short*)(W + O_XPWB))[d] = f2bf(W[I_V2XPW + d]);
  } else if (i < 1835008){
    long long d = i - 1310720;
    ((unsigned short*)(W + O_OUTWB))[d] = f2bf(W[I_V2OUTW + d]);
  } else if (i < 1867776){
    long long d = i - 1835008;
    ((unsigned short*)(W + O_CV2WB))[d] = f2bf(W[I_CV2W + d]);
  } else if (i < 2015232){
    long long d = i - 1867776;
    int c = (int)(d / 1152), r = (int)(d % 1152), tap = r / 128, i2 = r % 128;
    ((unsigned short*)(W + O_CV1WB))[d] = f2bf(W[I_CV1W + ((long long)(c*128 + i2))*9 + tap]);
  } else if (i < 3194880){
    long long d = i - 2015232;
    int c = (int)(d / 2304), r = (int)(d % 2304), tap = r / 256, i2 = r % 256;
    ((unsigned short*)(W + O_FCW2))[d] = f2bf(W[I_FCW + ((long long)(c*256 + i2))*9 + tap]);
  }
}

// im2col
template<int CIN>
__global__ void k_im2colT(const unsigned short* __restrict__ XT, unsigned short* __restrict__ B2){
  int r = blockIdx.x*256 + threadIdx.x;
  if (r >= 9*CIN) return;
  int p = blockIdx.y;
  int tap = r / CIN, d = r % CIN;
  int dy = tap/3 - 1, dx = tap%3 - 1;
  int y = p >> 6, x = p & 63;
  int yy = y + dy, xx = x + dx;
  unsigned short v = 0;
  if (yy >= 0 && yy < 64 && xx >= 0 && xx < 64) v = XT[(long long)(yy*64+xx)*CIN + d];
  B2[(long long)p*(9*CIN) + r] = v;
}

// =============== transposes ===============
__global__ void k_transpose(const float* __restrict__ in, float* __restrict__ out,
                            int rows, int cols, long long instride, long long outstride){
  __shared__ float tile[32][33];
  int tx = threadIdx.x & 31, ty = threadIdx.x >> 5;
  long long c0 = (long long)blockIdx.x*32, r0 = (long long)blockIdx.y*32;
  #pragma unroll
  for (int i=0;i<32;i+=8){
    long long r = r0 + ty + i, c = c0 + tx;
    if (r < rows && c < cols) tile[ty+i][tx] = in[r*instride + c];
  }
  __syncthreads();
  #pragma unroll
  for (int i=0;i<32;i+=8){
    long long r = r0 + tx, c = c0 + ty + i;
    if (r < rows && c < cols) out[c*outstride + r] = tile[tx][ty+i];
  }
}

__global__ void k_transpose_dual(const float* __restrict__ in, float* __restrict__ outF,
                                 unsigned short* __restrict__ outB,
                                 int rows, int cols, long long instride, long long outstride){
  __shared__ float tile[32][33];
  int tx = threadIdx.x & 31, ty = threadIdx.x >> 5;
  long long c0 = (long long)blockIdx.x*32, r0 = (long long)blockIdx.y*32;
  #pragma unroll
  for (int i=0;i<32;i+=8){
    long long r = r0 + ty + i, c = c0 + tx;
    if (r < rows && c < cols) tile[ty+i][tx] = in[r*instride + c];
  }
  __syncthreads();
  #pragma unroll
  for (int i=0;i<32;i+=8){
    long long r = r0 + tx, c = c0 + ty + i;
    if (r < rows && c < cols){
      float v = tile[tx][ty+i];
      if (outF) outF[c*outstride + r] = v;
      outB[c*outstride + r] = f2bf(v);
    }
  }
}

// =============== bf16 MFMA GEMM ===============
template<int MODE>
__global__ __launch_bounds__(256)
void k_gemm_bt(const unsigned short* __restrict__ A, const unsigned short* __restrict__ B,
               int K, int N, float* __restrict__ Cout, const float* __restrict__ bias,
               const float* __restrict__ res, const unsigned int* flagp, void* dout){
  constexpr int LDK = 72;
  __shared__ unsigned short As[128*LDK], Bs[128*LDK];
  int m0 = blockIdx.x*128, n0 = blockIdx.y*128;
  int tid = threadIdx.x;
  int wave = tid >> 6, lane = tid & 63, quad = lane >> 4, l16 = lane & 15;
  int wm = wave >> 1, wn = wave & 1;
  f32x4 acc[4][4];
  #pragma unroll
  for (int a=0;a<4;++a)
    #pragma unroll
    for (int b=0;b<4;++b) acc[a][b] = (f32x4){0.f,0.f,0.f,0.f};
  int srow = tid >> 1, shalf = (tid & 1)*32;
  for (int kt = 0; kt < K; kt += 64){
    const u16x8* ga = (const u16x8*)(A + (long long)(m0+srow)*K + kt + shalf);
    const u16x8* gb = (const u16x8*)(B + (long long)(n0+srow)*K + kt + shalf);
    u16x8* da = (u16x8*)&As[srow*LDK + shalf];
    u16x8* db = (u16x8*)&Bs[srow*LDK + shalf];
    #pragma unroll
    for (int c=0;c<4;++c){ da[c] = ga[c]; db[c] = gb[c]; }
    __syncthreads();
    #pragma unroll
    for (int ks=0; ks<64; ks+=32){
      bf16x8 af[4], bfr[4];
      #pragma unroll
      for (int mi=0;mi<4;++mi)
        af[mi] = *(const bf16x8*)&As[(wm*64 + mi*16 + l16)*LDK + ks + quad*8];
      #pragma unroll
      for (int ni=0;ni<4;++ni)
        bfr[ni] = *(const bf16x8*)&Bs[(wn*64 + ni*16 + l16)*LDK + ks + quad*8];
      #pragma unroll
      for (int mi=0;mi<4;++mi)
        #pragma unroll
        for (int ni=0;ni<4;++ni)
          acc[mi][ni] = __builtin_amdgcn_mfma_f32_16x16x32_bf16(af[mi], bfr[ni], acc[mi][ni], 0, 0, 0);
    }
    __syncthreads();
  }
  bool bf = (MODE == 2) ? ((*flagp) == 0x3F803F80u) : false;
  #pragma unroll
  for (int mi=0;mi<4;++mi){
    #pragma unroll
    for (int ni=0;ni<4;++ni){
      #pragma unroll
      for (int r=0;r<4;++r){
        int m = m0 + wm*64 + mi*16 + quad*4 + r;
        int n = n0 + wn*64 + ni*16 + l16;
        float v = acc[mi][ni][r];
        if (MODE == 1) v += bias[m];
        if (MODE == 2){
          v += res[(long long)m*N + n];
          if (bf) ((unsigned short*)dout)[(long long)m*N + n] = f2bf(v);
          else    ((float*)dout)[(long long)m*N + n] = v;
        } else {
          Cout[(long long)m*N + n] = v;
        }
      }
    }
  }
}

// =============== chunked selective-scan (3 passes) ===============
// UB16: u read from bf16 array at o_xt (same values both passes -> decomposition consistent)
template<int DCH, int TD, int L, int LG, int T, int R, int CROWS, int STRIDE, int BOFF, int SROWS, bool UB16>
__global__ void k_scan_p1(float* __restrict__ W, long long o_dbl, long long o_xt,
                          long long o_p, long long o_s,
                          long long i_dtw, long long i_dtb, long long i_alog){
  constexpr int NT = DCH/TD;
  int k = blockIdx.x / NT, tile = blockIdx.x % NT;
  int c = blockIdx.y;
  int t = threadIdx.x;
  int dch = tile*TD + t;
  __shared__ __align__(16) float stage[T*STRIDE];
  const float* dbl = W + o_dbl + (long long)k*CROWS*L;
  const int Lm1 = L-1, mask = (1<<LG)-1;
  for (int idx = t; idx < SROWS*T; idx += TD){
    int row = idx / T, col = idx % T;
    int l = c*T + col;
    int cc = scan_addr(k, l, LG, Lm1);
    int slot = (row < R) ? row : (BOFF + row - R);
    stage[col*STRIDE + slot] = dbl[(long long)row*L + cc];
  }
  __syncthreads();
  float w[R], A[16], s[16];
  #pragma unroll
  for (int r=0;r<R;++r) w[r] = W[i_dtw + (long long)(k*DCH+dch)*R + r];
  float bias = W[i_dtb + k*DCH + dch];
  bool pat = true;
  #pragma unroll
  for (int n=0;n<16;++n){
    A[n] = -expf(W[i_alog + (long long)(k*DCH+dch)*16 + n]);
    pat = pat && (fabsf(A[n] + (float)(n+1)) <= 1e-3f*(float)(n+1));
    s[n] = 0.f;
  }
  const float* XT = W + o_xt;
  const unsigned short* XTB = (const unsigned short*)(W + o_xt);
  float dtsum = 0.f;
  for (int j0=0;j0<T;j0+=8){
    float uv[8];
    #pragma unroll
    for (int q=0;q<8;++q){
      int l = c*T + j0 + q;
      int p_ = (k&2)? (Lm1-l) : l;
      int ua = (k&1)? (((p_&mask)<<LG)|(p_>>LG)) : p_;
      if (UB16) uv[q] = __uint_as_float(((unsigned int)XTB[(long long)ua*DCH + dch]) << 16);
      else      uv[q] = XT[(long long)ua*DCH + dch];
    }
    #pragma unroll
    for (int q=0;q<8;++q){
      int j = j0 + q;
      float x = bias;
      if (R == 2){
        x += stage[j*STRIDE]*w[0] + stage[j*STRIDE+1]*w[1];
      } else {
        const f32x4* dp = (const f32x4*)&stage[j*STRIDE];
        #pragma unroll
        for (int r4=0; r4<R/4; ++r4){
          f32x4 v = dp[r4];
          x += v[0]*w[r4*4] + v[1]*w[r4*4+1] + v[2]*w[r4*4+2] + v[3]*w[r4*4+3];
        }
      }
      float e = __expf(x);
      float dt = (x > 15.f) ? x : __logf(1.f + e);
      dtsum += dt;
      float du = dt*uv[q];
      const f32x4* bp = (const f32x4*)&stage[j*STRIDE + BOFF];
      if (pat){
        float qq = 1.f/(1.f + e);
        float q2 = qq*qq, q4 = q2*q2;
        f32x4 f0; f0[0]=qq; f0[1]=q2; f0[2]=q2*qq; f0[3]=q4;
        f32x4 f1 = f0*q4, f2 = f1*q4, f3 = f2*q4;
        f32x4 B0 = bp[0], B1 = bp[1], B2 = bp[2], B3 = bp[3];
        #pragma unroll
        for (int i=0;i<4;++i){
          s[i]    = s[i]   *f0[i] + du*B0[i];
          s[4+i]  = s[4+i] *f1[i] + du*B1[i];
          s[8+i]  = s[8+i] *f2[i] + du*B2[i];
          s[12+i] = s[12+i]*f3[i] + du*B3[i];
        }
      } else {
        #pragma unroll
        for (int n4=0;n4<4;++n4){
          f32x4 B = bp[n4];
          #pragma unroll
          for (int i=0;i<4;++i){ int n=n4*4+i; s[n] = s[n]*__expf(dt*A[n]) + du*B[i]; }
        }
      }
    }
  }
  float* P = W + o_p; float* S = W + o_s;
  long long base = (long long)c*(4LL*DCH*16) + (long long)k*DCH*16 + (long long)dch*16;
  #pragma unroll
  for (int n=0;n<16;++n){ P[base+n] = __expf(dtsum*A[n]); S[base+n] = s[n]; }
}

template<int NSTATE, int CH>
__global__ void k_carry(float* __restrict__ W, long long o_p, long long o_s){
  int idx = blockIdx.x*256 + threadIdx.x;
  if (idx >= NSTATE) return;
  const float* P = W + o_p; float* S = W + o_s;
  float h = 0.f;
  for (int c=0;c<CH;++c){
    float p = P[(long long)c*NSTATE + idx];
    float s = S[(long long)c*NSTATE + idx];
    S[(long long)c*NSTATE + idx] = h;
    h = h*p + s;
  }
}

template<int DCH, int TD, int L, int LG, int T, int R, int CROWS, int STRIDE, int BOFF, bool UB16>
__global__ void k_scan_p3(float* __restrict__ W, long long o_dbl, long long o_xt,
                          long long o_s, long long o_ys,
                          long long i_dtw, long long i_dtb, long long i_alog, long long i_dd){
  constexpr int NT = DCH/TD;
  int k = blockIdx.x / NT, tile = blockIdx.x % NT;
  int c = blockIdx.y;
  int t = threadIdx.x;
  int dch = tile*TD + t;
  __shared__ __align__(16) float stage[T*STRIDE];
  const float* dbl = W + o_dbl + (long long)k*CROWS*L;
  const int Lm1 = L-1, mask = (1<<LG)-1;
  for (int idx = t; idx < CROWS*T; idx += TD){
    int row = idx / T, col = idx % T;
    int l = c*T + col;
    int cc = scan_addr(k, l, LG, Lm1);
    int slot = (row < R) ? row : (BOFF + row - R);
    stage[col*STRIDE + slot] = dbl[(long long)row*L + cc];
  }
  __syncthreads();
  float w[R], A[16], s[16];
  #pragma unroll
  for (int r=0;r<R;++r) w[r] = W[i_dtw + (long long)(k*DCH+dch)*R + r];
  float bias = W[i_dtb + k*DCH + dch];
  float Dv = W[i_dd + k*DCH + dch];
  long long sbase = (long long)c*(4LL*DCH*16) + (long long)k*DCH*16 + (long long)dch*16;
  bool pat = true;
  #pragma unroll
  for (int n=0;n<16;++n){
    A[n] = -expf(W[i_alog + (long long)(k*DCH+dch)*16 + n]);
    pat = pat && (fabsf(A[n] + (float)(n+1)) <= 1e-3f*(float)(n+1));
    s[n] = W[o_s + sbase + n];
  }
  const float* XT = W + o_xt;
  const unsigned short* XTB = (const unsigned short*)(W + o_xt);
  __half* Y = (__half*)(W + o_ys);
  for (int j0=0;j0<T;j0+=8){
    float uv[8];
    #pragma unroll
    for (int q=0;q<8;++q){
      int l = c*T + j0 + q;
      int p_ = (k&2)? (Lm1-l) : l;
      int ua = (k&1)? (((p_&mask)<<LG)|(p_>>LG)) : p_;
      if (UB16) uv[q] = __uint_as_float(((unsigned int)XTB[(long long)ua*DCH + dch]) << 16);
      else      uv[q] = XT[(long long)ua*DCH + dch];
    }
    #pragma unroll
    for (int q=0;q<8;++q){
      int j = j0 + q;
      int l = c*T + j;
      float x = bias;
      if (R == 2){
        x += stage[j*STRIDE]*w[0] + stage[j*STRIDE+1]*w[1];
      } else {
        const f32x4* dp = (const f32x4*)&stage[j*STRIDE];
        #pragma unroll
        for (int r4=0; r4<R/4; ++r4){
          f32x4 v = dp[r4];
          x += v[0]*w[r4*4] + v[1]*w[r4*4+1] + v[2]*w[r4*4+2] + v[3]*w[r4*4+3];
        }
      }
      float e = __expf(x);
      float dt = (x > 15.f) ? x : __logf(1.f + e);
      float du = dt*uv[q];
      float y = Dv*uv[q];
      const f32x4* bp = (const f32x4*)&stage[j*STRIDE + BOFF];
      const f32x4* cp = (const f32x4*)&stage[j*STRIDE + BOFF + 16];
      if (pat){
        float qq = 1.f/(1.f + e);
        float q2 = qq*qq, q4 = q2*q2;
        f32x4 f0; f0[0]=qq; f0[1]=q2; f0[2]=q2*qq; f0[3]=q4;
        f32x4 f1 = f0*q4, f2 = f1*q4, f3 = f2*q4;
        f32x4 B0 = bp[0], B1 = bp[1], B2 = bp[2], B3 = bp[3];
        f32x4 C0 = cp[0], C1 = cp[1], C2 = cp[2], C3 = cp[3];
        #pragma unroll
        for (int i=0;i<4;++i){
          s[i]    = s[i]   *f0[i] + du*B0[i];
          s[4+i]  = s[4+i] *f1[i] + du*B1[i];
          s[8+i]  = s[8+i] *f2[i] + du*B2[i];
          s[12+i] = s[12+i]*f3[i] + du*B3[i];
        }
        #pragma unroll
        for (int i=0;i<4;++i)
          y += s[i]*C0[i] + s[4+i]*C1[i] + s[8+i]*C2[i] + s[12+i]*C3[i];
      } else {
        #pragma unroll
        for (int n4=0;n4<4;++n4){
          f32x4 B = bp[n4], C = cp[n4];
          #pragma unroll
          for (int i=0;i<4;++i){
            int n = n4*4+i;
            s[n] = s[n]*__expf(dt*A[n]) + du*B[i];
            y += s[n]*C[i];
          }
        }
      }
      Y[(long long)l*(4*DCH) + k*DCH + dch] = __float2half(y);
    }
  }
}

// =============== stage A: c0 ===============
__global__ void k_c0(float* __restrict__ W){
  int i = blockIdx.x*256 + threadIdx.x; if (i >= 32*512) return;
  int c = i >> 9, l = i & 511;
  float acc = W[I_C0B + c];
  for (int ii=0; ii<18; ++ii)
    for (int j=0; j<3; ++j){
      int p = l-1+j;
      if (p >= 0 && p < 512) acc += W[I_LD + ii*512 + p] * W[I_C0W + (c*18+ii)*3 + j];
    }
  W[O_X0 + i] = acc;
}

// =============== stage B: mamba2 ===============
__global__ void k_zxf(float* __restrict__ W){
  int j = blockIdx.x;
  int t = threadIdx.x, l = t & 31, kc = t >> 5;
  __shared__ float wrow[512];
  for (int idx = t; idx < 512; idx += 256) wrow[idx] = W[I_MINW + (long long)j*512 + idx];
  __syncthreads();
  float acc = 0.f;
  const float* u = W + O_X0 + l*512;
  for (int d = kc*64; d < kc*64 + 64; ++d) acc += u[d]*wrow[d];
  __shared__ float red[256];
  red[t] = acc; __syncthreads();
  if (kc == 0){
    float s = 0.f;
    #pragma unroll
    for (int q=0;q<8;++q) s += red[l + q*32];
    W[O_ZX + l*2320 + j] = s;
  }
}

__global__ void k_conv4(float* __restrict__ W){
  int i = blockIdx.x*256 + threadIdx.x; if (i >= 32*1280) return;
  int l = i / 1280, c = i % 1280;
  float acc = W[I_MCONVB + c];
  for (int j=0; j<4; ++j){
    int p = l-3+j;
    if (p >= 0) acc += W[O_ZX + p*2320 + 1024 + c] * W[I_MCONVW + c*4 + j];
  }
  W[O_XBCC + l*1280 + c] = siluf(acc);
}

__global__ void k_dtm(float* __restrict__ W){
  int i = blockIdx.x*256 + threadIdx.x; if (i >= 512) return;
  int l = i >> 4, h = i & 15;
  W[O_DTM + i] = softplusf(W[O_ZX + l*2320 + 2304 + h] + W[I_MDTB + h]);
}

__global__ void k_mscan(float* __restrict__ W){
  int h = blockIdx.x >> 6, pp = blockIdx.x & 63;
  int lane = threadIdx.x;
  float A = -expf(W[I_MALOG + h]);
  float Dv = W[I_MD + h];
  float s0 = 0.f, s1 = 0.f;
  for (int l=0; l<32; ++l){
    float dt = W[O_DTM + l*16 + h];
    float xv = W[O_XBCC + l*1280 + h*64 + pp];
    float dA = expf(dt*A);
    float b0 = W[O_XBCC + l*1280 + 1024 + lane];
    float b1 = W[O_XBCC + l*1280 + 1088 + lane];
    float c0 = W[O_XBCC + l*1280 + 1152 + lane];
    float c1 = W[O_XBCC + l*1280 + 1216 + lane];
    float du = dt*xv;
    s0 = s0*dA + du*b0;
    s1 = s1*dA + du*b1;
    float part = s0*c0 + s1*c1;
    for (int off=32; off; off>>=1) part += __shfl_xor(part, off, 64);
    if (lane == 0) W[O_TPRE + l*1024 + h*64 + pp] = part + Dv*xv;
  }
}

__global__ void k_gaterms(float* __restrict__ W){
  int l = blockIdx.x, t = threadIdx.x;
  float vals[4]; float ss = 0.f;
  for (int q=0; q<4; ++q){
    int c = t + q*256;
    float z = W[O_ZX + l*2320 + c];
    float y = W[O_TPRE + l*1024 + c];
    float v = y * siluf(z);
    vals[q] = v; ss += v*v;
  }
  for (int off=32; off; off>>=1) ss += __shfl_xor(ss, off, 64);
  __shared__ float sm[4];
  if ((t & 63) == 0) sm[t>>6] = ss;
  __syncthreads();
  float tot = sm[0]+sm[1]+sm[2]+sm[3];
  float r = rsqrtf(tot/1024.f + 1e-5f);
  for (int q=0; q<4; ++q){
    int c = t + q*256;
    W[O_TG + l*1024 + c] = vals[q]*r*W[I_MNORMW + c];
  }
}

__global__ void k_outmf(float* __restrict__ W){
  int d = blockIdx.x;
  int t = threadIdx.x, l = t & 31, kc = t >> 5;
  __shared__ float wrow[1024];
  for (int idx = t; idx < 1024; idx += 256) wrow[idx] = W[I_MOUTW + (long long)d*1024 + idx];
  __syncthreads();
  float acc = 0.f;
  const float* tg = W + O_TG + l*1024;
  for (int c = kc*128; c < kc*128 + 128; ++c) acc += tg[c]*wrow[c];
  __shared__ float red[256];
  red[t] = acc; __syncthreads();
  if (kc == 0){
    float s = 0.f;
    #pragma unroll
    for (int q=0;q<8;++q) s += red[l + q*32];
    W[O_OUTM + l*512 + d] = s;
  }
}

// =============== stage C: c1 ===============
__global__ void k_c1f(float* __restrict__ W){
  int o = blockIdx.x;
  int t = threadIdx.x, l = t & 31, kc = t >> 5;
  __shared__ float wrow[1536];
  for (int idx = t; idx < 1536; idx += 256) wrow[idx] = W[I_C1W + (long long)o*1536 + idx];
  __syncthreads();
  float acc = 0.f;
  for (int ii = kc*64; ii < kc*64 + 64; ++ii){
    #pragma unroll
    for (int j=0;j<3;++j){
      int p = l-1+j;
      if (p >= 0 && p < 32) acc += W[O_OUTM + p*512 + ii] * wrow[ii*3+j];
    }
  }
  __shared__ float red[256];
  red[t] = acc; __syncthreads();
  if (kc == 0){
    float s = W[I_C1B + o];
    #pragma unroll
    for (int q=0;q<8;++q) s += red[l + q*32];
    W[O_Y1 + o*32 + l] = s;
  }
}

// =============== vssblock 1 ===============
__global__ void k_ln1(float* __restrict__ W){
  int l = blockIdx.x*256 + threadIdx.x; if (l >= 1024) return;
  float s = 0.f, s2 = 0.f;
  for (int c=0; c<32; ++c){ float v = W[O_Y1 + l*32 + c]; s += v; s2 += v*v; }
  float mu = s/32.f, var = s2/32.f - mu*mu, rs = rsqrtf(var + 1e-5f);
  for (int c=0; c<32; ++c){
    float v = W[O_Y1 + l*32 + c];
    W[O_H1 + l*32 + c] = (v-mu)*rs*W[I_V1LNW + c] + W[I_V1LNB + c];
  }
}

__global__ void k_xz1(float* __restrict__ W){
  int i = blockIdx.x*256 + threadIdx.x; if (i >= 1024*128) return;
  int l = i >> 7, j = i & 127;
  float acc = 0.f;
  for (int c=0; c<32; ++c) acc += W[O_H1 + l*32 + c] * W[I_V1INW + j*32 + c];
  W[O_XZ1 + i] = acc;
}

__global__ void k_dwcs1(float* __restrict__ W){
  int i = blockIdx.x*256 + threadIdx.x; if (i >= 64*1024) return;
  int ch = i >> 10, pix = i & 1023, a = pix >> 5, b = pix & 31;
  float acc = W[I_V1CONVB + ch];
  for (int dy=0; dy<3; ++dy){
    int aa = a+dy-1; if (aa < 0 || aa > 31) continue;
    for (int dx=0; dx<3; ++dx){
      int bb = b+dx-1; if (bb < 0 || bb > 31) continue;
      acc += W[O_XZ1 + (aa*32+bb)*128 + ch] * W[I_V1CONVW + ch*9 + dy*3 + dx];
    }
  }
  W[O_XC1 + i] = siluf(acc);
}

__global__ void k_dbl1(float* __restrict__ W){
  int i = blockIdx.x*256 + threadIdx.x; if (i >= 4*34*1024) return;
  int k = i / 34816, r = i % 34816, c = r / 1024, l = r % 1024;
  float acc = 0.f;
  for (int d=0; d<64; ++d) acc += W[O_XC1 + d*1024 + l] * W[I_V1XPW + (k*34+c)*64 + d];
  W[O_DBL1 + (k*34+c)*1024 + l] = acc;
}

__global__ void k_comb1(float* __restrict__ W){
  int l = blockIdx.x, dch = threadIdx.x;
  int t1 = ((l & 31) << 5) | (l >> 5);
  const __half* Y = (const __half*)(W + O_YS1);
  float x = __half2float(Y[l*256 + dch])
          + __half2float(Y[t1*256 + 64 + dch])
          + __half2float(Y[(1023-l)*256 + 128 + dch])
          + __half2float(Y[(1023-t1)*256 + 192 + dch]);
  float s = x, s2 = x*x;
  for (int off=32; off; off>>=1){ s += __shfl_xor(s, off, 64); s2 += __shfl_xor(s2, off, 64); }
  float mu = s/64.f, var = s2/64.f - mu*mu, rs = rsqrtf(var + 1e-5f);
  float yn = (x-mu)*rs*W[I_V1ONW + dch] + W[I_V1ONB + dch];
  float z = W[O_XZ1 + l*128 + 64 + dch];
  W[O_G1 + l*64 + dch] = yn * siluf(z);
}

__global__ void k_oproj1(float* __restrict__ W){
  int i = blockIdx.x*256 + threadIdx.x; if (i >= 1024*32) return;
  int l = i >> 5, c = i & 31;
  float acc = W[O_Y1 + i];
  for (int d=0; d<64; ++d) acc += W[O_G1 + l*64 + d] * W[I_V1OUTW + c*64 + d];
  W[O_OUTD + i] = acc;
}

// =============== stage E: conv stack ===============
__global__ void k_dw1(float* __restrict__ W){
  int i = blockIdx.x*256 + threadIdx.x; if (i >= 32*1024) return;
  int c = i >> 10, pix = i & 1023, a = pix >> 5, b = pix & 31;
  float acc = W[I_DW1B + c];
  for (int dy=0; dy<3; ++dy){
    int aa = a+dy-1; if (aa < 0 || aa > 31) continue;
    for (int dx=0; dx<3; ++dx){
      int bb = b+dx-1; if (bb < 0 || bb > 31) continue;
      acc += W[O_OUTD + (aa*32+bb)*32 + c] * W[I_DW1W + c*9 + dy*3 + dx];
    }
  }
  W[O_E1 + i] = acc;
}

__global__ void k_pw1(float* __restrict__ W){
  int i = blockIdx.x*256 + threadIdx.x; if (i >= 64*1024) return;
  int o = i >> 10, pix = i & 1023;
  float acc = W[I_PW1B + o];
  for (int c=0; c<32; ++c) acc += W[I_PW1W + o*32 + c] * W[O_E1 + c*1024 + pix];
  W[O_E2 + i] = acc;
}

__global__ void k_dw2(float* __restrict__ W){
  int i = blockIdx.x*256 + threadIdx.x; if (i >= 64*1024) return;
  int c = i >> 10, pix = i & 1023, a = pix >> 5, b = pix & 31;
  float acc = W[I_DW2B + c];
  for (int dy=0; dy<3; ++dy){
    int aa = a+dy-1; if (aa < 0 || aa > 31) continue;
    for (int dx=0; dx<3; ++dx){
      int bb = b+dx-1; if (bb < 0 || bb > 31) continue;
      acc += W[O_E2 + c*1024 + aa*32 + bb] * W[I_DW2W + c*9 + dy*3 + dx];
    }
  }
  W[O_E3 + i] = acc;
}

__global__ void k_pw2(float* __restrict__ W){
  int i = blockIdx.x*256 + threadIdx.x; if (i >= 128*1024) return;
  int o = i >> 10, pix = i & 1023;
  float acc = W[I_PW2B + o];
  for (int c=0; c<64; ++c) acc += W[I_PW2W + o*64 + c] * W[O_E3 + c*1024 + pix];
  W[O_E4 + i] = acc;
}

DEV void rs_coef(int o, int n, int& i0, int& i1, float& w0, float& w1){
  float src = 0.5f*(float)o - 0.25f;
  float f = floorf(src);
  float fr = src - f;
  int a = (int)f;
  if (a < 0){ i0 = 0; i1 = 0; w0 = 0.f; w1 = 1.f; }
  else if (a >= n-1){ i0 = n-1; i1 = n-1; w0 = 1.f; w1 = 0.f; }
  else { i0 = a; i1 = a+1; w0 = 1.f-fr; w1 = fr; }
}

__global__ void k_resize(float* __restrict__ W){
  int i = blockIdx.x*256 + threadIdx.x; if (i >= 128*4096) return;
  int c = i >> 12, pix = i & 4095, y = pix >> 6, x = pix & 63;
  int iy0, iy1, ix0, ix1; float wy0, wy1, wx0, wx1;
  rs_coef(y, 32, iy0, iy1, wy0, wy1);
  rs_coef(x, 32, ix0, ix1, wx0, wx1);
  const float* in = W + O_E4 + c*1024;
  float v = wy0*(wx0*in[iy0*32+ix0] + wx1*in[iy0*32+ix1])
          + wy1*(wx0*in[iy1*32+ix0] + wx1*in[iy1*32+ix1]);
  W[O_E5 + i] = v;
}

// =============== stage F: vssblock2 ===============
__global__ void k_ln2(float* __restrict__ W){
  int l = blockIdx.x, t = threadIdx.x;
  float v0 = W[O_E8 + (long long)t*4096 + l];
  float v1 = W[O_E8 + (long long)(t+256)*4096 + l];
  float s = v0+v1, s2 = v0*v0 + v1*v1;
  for (int off=32; off; off>>=1){ s += __shfl_xor(s, off, 64); s2 += __shfl_xor(s2, off, 64); }
  __shared__ float a[4], b[4];
  if ((t & 63) == 0){ a[t>>6] = s; b[t>>6] = s2; }
  __syncthreads();
  float S = a[0]+a[1]+a[2]+a[3], S2 = b[0]+b[1]+b[2]+b[3];
  float mu = S/512.f, var = S2/512.f - mu*mu, rs = rsqrtf(var + 1e-5f);
  unsigned short* H = (unsigned short*)(W + O_LN2);
  H[(long long)l*512 + t]     = f2bf((v0-mu)*rs*W[I_V2LNW + t]     + W[I_V2LNB + t]);
  H[(long long)l*512 + t+256] = f2bf((v1-mu)*rs*W[I_V2LNW + t+256] + W[I_V2LNB + t+256]);
}

__global__ void k_dwcs2(float* __restrict__ W){
  long long i = (long long)blockIdx.x*256 + threadIdx.x;
  int ch = (int)(i >> 12), pix = (int)(i & 4095), a = pix >> 6, b = pix & 63;
  float acc = W[I_V2CONVB + ch];
  const float* xp = W + O_XT2 + (long long)ch*4096;
  for (int dy=0; dy<3; ++dy){
    int aa = a+dy-1; if (aa < 0 || aa > 63) continue;
    for (int dx=0; dx<3; ++dx){
      int bb = b+dx-1; if (bb < 0 || bb > 63) continue;
      acc += xp[aa*64+bb] * W[I_V2CONVW + ch*9 + dy*3 + dx];
    }
  }
  W[O_XC2 + i] = siluf(acc);
}

__global__ void k_comb2(float* __restrict__ W){
  int l = blockIdx.x, t = threadIdx.x;
  int t1 = ((l & 63) << 6) | (l >> 6);
  const __half* Y = (const __half*)(W + O_YS2);
  float v[4]; float s = 0.f, s2 = 0.f;
  for (int q=0; q<4; ++q){
    int dch = t + q*256;
    float x = __half2float(Y[(long long)l*4096 + dch])
            + __half2float(Y[(long long)t1*4096 + 1024 + dch])
            + __half2float(Y[(long long)(4095-l)*4096 + 2048 + dch])
            + __half2float(Y[(long long)(4095-t1)*4096 + 3072 + dch]);
    v[q] = x; s += x; s2 += x*x;
  }
  for (int off=32; off; off>>=1){ s += __shfl_xor(s, off, 64); s2 += __shfl_xor(s2, off, 64); }
  __shared__ float a[4], b[4];
  if ((t & 63) == 0){ a[t>>6] = s; b[t>>6] = s2; }
  __syncthreads();
  float S = a[0]+a[1]+a[2]+a[3], S2 = b[0]+b[1]+b[2]+b[3];
  float mu = S/1024.f, var = S2/1024.f - mu*mu, rs = rsqrtf(var + 1e-5f);
  unsigned short* G = (unsigned short*)(W + O_G2);
  for (int q=0; q<4; ++q){
    int dch = t + q*256;
    float yn = (v[q]-mu)*rs*W[I_V2ONW + dch] + W[I_V2ONB + dch];
    float z = W[O_XZ2 + (long long)l*2048 + 1024 + dch];
    G[(long long)l*1024 + dch] = f2bf(yn * siluf(z));
  }
}

// =============== launch ===============
extern "C" void kernel_launch(void* const* d_in, const int* in_sizes, int n_in,
                              void* d_out, int out_size, void* d_ws, size_t ws_size,
                              hipStream_t stream){
  if (ws_size < (size_t)WS_FLOATS * sizeof(float)) return;
  float* W = (float*)d_ws;
  PtrTab tab;
  for (int i=0; i<53; ++i) tab.p[i] = d_in[i];
  const unsigned int* flagp = (const unsigned int*)d_in[9];

  k_ingest<<<INGEST_BLOCKS, 256, 0, stream>>>(tab, W);
  k_prep  <<<12480, 256, 0, stream>>>(W);

  k_c0    <<<64, 256, 0, stream>>>(W);
  k_zxf   <<<2320, 256, 0, stream>>>(W);
  k_conv4 <<<160, 256, 0, stream>>>(W);
  k_dtm   <<<2, 256, 0, stream>>>(W);
  k_mscan <<<1024, 64, 0, stream>>>(W);
  k_gaterms<<<32, 256, 0, stream>>>(W);
  k_outmf <<<512, 256, 0, stream>>>(W);
  k_c1f   <<<1024, 256, 0, stream>>>(W);
  k_ln1   <<<4, 256, 0, stream>>>(W);
  k_xz1   <<<512, 256, 0, stream>>>(W);
  k_dwcs1 <<<256, 256, 0, stream>>>(W);
  k_dbl1  <<<544, 256, 0, stream>>>(W);
  // vss1 chunked scan (T=64, f32 u)
  k_transpose<<<dim3(32, 2), 256, 0, stream>>>(W + O_XC1, W + O_XT1, 64, 1024, 1024, 64);
  k_scan_p1<64,64,1024,5,64,2,34,40,4,18,false><<<dim3(4,16), 64, 0, stream>>>(W, O_DBL1, O_XT1, O_P1, O_S1,
                                                                 I_V1DTW, I_V1DTB, I_V1ALOG);
  k_carry<4096,16><<<16, 256, 0, stream>>>(W, O_P1, O_S1);
  k_scan_p3<64,64,1024,5,64,2,34,40,4,false><<<dim3(4,16), 64, 0, stream>>>(W, O_DBL1, O_XT1, O_S1, O_YS1,
                                                                 I_V1DTW, I_V1DTB, I_V1ALOG, I_V1D);
  k_comb1 <<<1024, 64, 0, stream>>>(W);
  k_oproj1<<<128, 256, 0, stream>>>(W);
  k_dw1   <<<128, 256, 0, stream>>>(W);
  k_pw1   <<<256, 256, 0, stream>>>(W);
  k_dw2   <<<256, 256, 0, stream>>>(W);
  k_pw2   <<<512, 256, 0, stream>>>(W);
  k_resize<<<2048, 256, 0, stream>>>(W);
  // cv1 via MFMA
  k_transpose_dual<<<dim3(128, 4), 256, 0, stream>>>(W + O_E5, nullptr,
                      (unsigned short*)(W + O_E5TB), 128, 4096, 4096, 128);
  k_im2colT<128><<<dim3(5, 4096), 256, 0, stream>>>((const unsigned short*)(W + O_E5TB),
                      (unsigned short*)(W + O_CV1B2));
  k_gemm_bt<1><<<dim3(1, 32), 256, 0, stream>>>((const unsigned short*)(W + O_CV1WB),
                      (const unsigned short*)(W + O_CV1B2), 1152, 4096,
                      W + O_E6, W + I_CV1B, nullptr, nullptr, nullptr);
  // cv2 via MFMA
  k_transpose_dual<<<dim3(128, 4), 256, 0, stream>>>(W + O_E6, nullptr,
                      (unsigned short*)(W + O_E6TB), 128, 4096, 4096, 128);
  k_gemm_bt<1><<<dim3(2, 32), 256, 0, stream>>>((const unsigned short*)(W + O_CV2WB),
                      (const unsigned short*)(W + O_E6TB), 128, 4096,
                      W + O_E7, W + I_CV2B, nullptr, nullptr, nullptr);
  // fc via MFMA
  k_transpose_dual<<<dim3(128, 8), 256, 0, stream>>>(W + O_E7, nullptr,
                      (unsigned short*)(W + O_E7T), 256, 4096, 4096, 256);
  k_im2colT<256><<<dim3(9, 4096), 256, 0, stream>>>((const unsigned short*)(W + O_E7T),
                      (unsigned short*)(W + O_B2));
  k_gemm_bt<1><<<dim3(4, 32), 256, 0, stream>>>((const unsigned short*)(W + O_FCW2),
                      (const unsigned short*)(W + O_B2), 2304, 4096,
                      W + O_E8, W + I_FCB, nullptr, nullptr, nullptr);
  // vss2
  k_ln2   <<<4096, 256, 0, stream>>>(W);
  k_gemm_bt<0><<<dim3(32, 16), 256, 0, stream>>>((const unsigned short*)(W + O_LN2),
                      (const unsigned short*)(W + O_W2INB), 512, 2048,
                      W + O_XZ2, nullptr, nullptr, nullptr, nullptr);
  k_transpose<<<dim3(32, 128), 256, 0, stream>>>(W + O_XZ2, W + O_XT2, 4096, 1024, 2048, 4096); // XP[ch][pix]
  k_dwcs2 <<<16384, 256, 0, stream>>>(W);
  // XC2 -> bf16 XT only (scans read u from bf16 XT2B)
  k_transpose_dual<<<dim3(128, 32), 256, 0, stream>>>(W + O_XC2, nullptr,
                      (unsigned short*)(W + O_XT2B), 1024, 4096, 4096, 1024);
  k_gemm_bt<0><<<dim3(2, 32), 256, 0, stream>>>((const unsigned short*)(W + O_XPWB),
                      (const unsigned short*)(W + O_XT2B), 1024, 4096,
                      W + O_DBL2, nullptr, nullptr, nullptr, nullptr);
  // T=64 chunked scan (R10 config) with bf16 u
  k_scan_p1<1024,256,4096,6,64,32,64,68,32,48,true><<<dim3(16,64), 256, 0, stream>>>(W, O_DBL2, O_XT2B, O_P2, O_S2,
                                                                       I_V2DTW, I_V2DTB, I_V2ALOG);
  k_carry<65536,64><<<256, 256, 0, stream>>>(W, O_P2, O_S2);
  k_scan_p3<1024,256,4096,6,64,32,64,68,32,true><<<dim3(16,64), 256, 0, stream>>>(W, O_DBL2, O_XT2B, O_S2, O_YS2,
                                                                       I_V2DTW, I_V2DTB, I_V2ALOG, I_V2D);
  k_comb2 <<<4096, 256, 0, stream>>>(W);
  k_gemm_bt<2><<<dim3(4, 32), 256, 0, stream>>>((const unsigned short*)(W + O_OUTWB),
                      (const unsigned short*)(W + O_G2), 1024, 4096,
                      nullptr, nullptr, W + O_E8, flagp, d_out);
}

// Round 13
// 967.793 us; speedup vs baseline: 1.0471x; 1.0471x over previous
//
#include <hip/hip_runtime.h>
#include <hip/hip_bf16.h>
#include <hip/hip_fp16.h>
#include <math.h>

#define DEV static __device__ __forceinline__

DEV float siluf(float x){ return x / (1.f + expf(-x)); }
DEV float softplusf(float x){ return (x > 20.f) ? x : log1pf(__expf(x)); }

DEV unsigned short f2bf(float f){
  unsigned int u = __float_as_uint(f);
  unsigned int r = (u + 0x7FFFu + ((u >> 16) & 1u)) >> 16;
  return (unsigned short)r;
}

using bf16x8 = __attribute__((ext_vector_type(8))) short;
using u16x8  = __attribute__((ext_vector_type(8))) unsigned short;
using f32x4  = __attribute__((ext_vector_type(4))) float;

// ---------------- input arena offsets (floats) ----------------
constexpr long long I_LD=0, I_C0W=9216, I_C0B=10944, I_MINW=10976, I_MCONVW=1198816,
 I_MCONVB=1203936, I_MDTB=1205216, I_MALOG=1205232, I_MD=1205248, I_MNORMW=1205264,
 I_MOUTW=1206288, I_C1W=1730576, I_C1B=3303440, I_V1LNW=3304464, I_V1LNB=3304496,
 I_V1INW=3304528, I_V1CONVW=3308624, I_V1CONVB=3309200, I_V1XPW=3309264, I_V1DTW=3317968,
 I_V1DTB=3318480, I_V1ALOG=3318736, I_V1D=3322832, I_V1ONW=3323088, I_V1ONB=3323152,
 I_V1OUTW=3323216, I_DW1W=3325264, I_DW1B=3325552, I_PW1W=3325584, I_PW1B=3327632,
 I_DW2W=3327696, I_DW2B=3328272, I_PW2W=3328336, I_PW2B=3336528, I_CV1W=3336656,
 I_CV1B=3484112, I_CV2W=3484240, I_CV2B=3517008, I_FCW=3517264, I_FCB=4696912,
 I_V2LNW=4697424, I_V2LNB=4697936, I_V2INW=4698448, I_V2CONVW=5747024, I_V2CONVB=5756240,
 I_V2XPW=5757264, I_V2DTW=6019408, I_V2DTB=6150480, I_V2ALOG=6154576, I_V2D=6220112,
 I_V2ONW=6224208, I_V2ONB=6225232, I_V2OUTW=6226256;
constexpr long long TOTAL_IN = 6750544;
constexpr int INGEST_BLOCKS = (int)((TOTAL_IN + 255) / 256);
constexpr long long O_E8 = 6750544;                // (512,4096) f32, lives to the end
constexpr long long SCR  = 8847696;
// phase 1 (stages A-E)
constexpr long long O_X0=SCR+0, O_ZX=SCR+16384, O_XBCC=SCR+90624, O_DTM=SCR+131584,
 O_TPRE=SCR+132096, O_TG=SCR+164864, O_OUTM=SCR+197632, O_Y1=SCR+214016, O_H1=SCR+246784,
 O_XZ1=SCR+279552, O_XC1=SCR+410624, O_DBL1=SCR+476160, O_YS1=SCR+615424, O_G1=SCR+877568,
 O_OUTD=SCR+943104, O_E1=SCR+975872, O_E2=SCR+1008640, O_E3=SCR+1074176, O_E4=SCR+1139712,
 O_E5=SCR+1270784, O_E6=SCR+1795072, O_E7=SCR+2319360;
// vss1 scan scratch
constexpr long long O_XT1=SCR+3367936, O_P1=SCR+3433472, O_S1=SCR+3499008;   // S1 ends 3564544
// free gap 3564544..4000000
constexpr long long O_CV2WB=SCR+3564544;  // ends 3580928
constexpr long long O_CV1WB=SCR+3580928;  // ends 3654656
// fc/cv MFMA scratch (phase-1 tail)
constexpr long long O_FCW2=SCR+4000000;   // ends 4589824
constexpr long long O_E7T =SCR+4600000;   // ends 5124288
constexpr long long O_E6TB=O_E7T;
constexpr long long O_E5TB=O_E7T;
constexpr long long O_B2  =SCR+5242880;   // ends 9961472 (phase-1 only)
constexpr long long O_CV1B2=O_B2;
// phase 2 (stage F)
constexpr long long O_XZ2=SCR+0;                        // 4096x2048 f32 (z live till comb2)
constexpr long long O_XC2=SCR+8388608;                  // dwcs2 out f32 (dead after dual transpose)
constexpr long long O_P2 =O_XC2;                        // overlay: P written in scan pass 1
constexpr long long O_XT2=SCR+12582912;                 // XP[ch][pix] f32, then XT[pix][ch] f32
constexpr long long O_G2 =O_XT2;                        // bf16 G2 (comb2 out, XT2 dead)
constexpr long long O_DBL2=SCR+16777216;                // G[256][4096] f32 (ends 17825792, live in scans)
constexpr long long O_S2 =SCR+17825792;                 // (ends 22020096)
constexpr long long O_YS2=SCR+22020096;                 // fp16 ys (ends 30408704)
constexpr long long O_LN2=SCR+30408704;                 // bf16 LN2 (ends 31457280)
// bf16 weights / staging (top region, no overlap)
constexpr long long O_W2INB=SCR+32505856;               // ends 33030144
constexpr long long O_XPWB =SCR+33030144;               // ends 33161216
constexpr long long O_OUTWB=SCR+33161216;               // ends 33423360
constexpr long long O_XT2B =SCR+33423360;               // ends 35520512
constexpr long long WS_FLOATS = SCR + 36700160;

struct PtrTab { const void* p[53]; };

__constant__ long long c_inoff[53] = { 0, 9216, 10944, 10976, 1198816, 1203936, 1205216,
 1205232, 1205248, 1205264, 1206288, 1730576, 3303440, 3304464, 3304496, 3304528, 3308624,
 3309200, 3309264, 3317968, 3318480, 3318736, 3322832, 3323088, 3323152, 3323216, 3325264,
 3325552, 3325584, 3327632, 3327696, 3328272, 3328336, 3336528, 3336656, 3484112, 3484240,
 3517008, 3517264, 4696912, 4697424, 4697936, 4698448, 5747024, 5756240, 5757264, 6019408,
 6150480, 6154576, 6220112, 6224208, 6225232, 6226256 };

DEV int scan_addr(int k, int l, int lg, int Lm1){
  int p = (k & 2) ? (Lm1 - l) : l;
  int mask = (1 << lg) - 1;
  if (k & 1) p = ((p & mask) << lg) | (p >> lg);
  return p;
}

// =============== ingest ===============
__global__ void k_ingest(PtrTab t, float* __restrict__ W){
  long long idx = (long long)blockIdx.x*256 + threadIdx.x;
  if (idx >= TOTAL_IN) return;
  int j = 0;
  #pragma unroll
  for (int q=1; q<53; ++q) if (idx >= c_inoff[q]) j = q;
  int local = (int)(idx - c_inoff[j]);
  bool bf = (*(const unsigned int*)t.p[9]) == 0x3F803F80u;
  float v;
  if (bf){
    unsigned short u = ((const unsigned short*)t.p[j])[local];
    v = __uint_as_float(((unsigned int)u) << 16);
  } else {
    v = ((const float*)t.p[j])[local];
  }
  W[idx] = v;
}

// =============== merged weight prep ===============
__global__ void k_prep(float* __restrict__ W){
  long long i = (long long)blockIdx.x*256 + threadIdx.x;
  if (i < 1048576){
    ((unsigned short*)(W + O_W2INB))[i] = f2bf(W[I_V2INW + i]);
  } else if (i < 1310720){
    long long d = i - 1048576;
    ((unsigned short*)(W + O_XPWB))[d] = f2bf(W[I_V2XPW + d]);
  } else if (i < 1835008){
    long long d = i - 1310720;
    ((unsigned short*)(W + O_OUTWB))[d] = f2bf(W[I_V2OUTW + d]);
  } else if (i < 1867776){
    long long d = i - 1835008;
    ((unsigned short*)(W + O_CV2WB))[d] = f2bf(W[I_CV2W + d]);
  } else if (i < 2015232){
    long long d = i - 1867776;
    int c = (int)(d / 1152), r = (int)(d % 1152), tap = r / 128, i2 = r % 128;
    ((unsigned short*)(W + O_CV1WB))[d] = f2bf(W[I_CV1W + ((long long)(c*128 + i2))*9 + tap]);
  } else if (i < 3194880){
    long long d = i - 2015232;
    int c = (int)(d / 2304), r = (int)(d % 2304), tap = r / 256, i2 = r % 256;
    ((unsigned short*)(W + O_FCW2))[d] = f2bf(W[I_FCW + ((long long)(c*256 + i2))*9 + tap]);
  }
}

// im2col
template<int CIN>
__global__ void k_im2colT(const unsigned short* __restrict__ XT, unsigned short* __restrict__ B2){
  int r = blockIdx.x*256 + threadIdx.x;
  if (r >= 9*CIN) return;
  int p = blockIdx.y;
  int tap = r / CIN, d = r % CIN;
  int dy = tap/3 - 1, dx = tap%3 - 1;
  int y = p >> 6, x = p & 63;
  int yy = y + dy, xx = x + dx;
  unsigned short v = 0;
  if (yy >= 0 && yy < 64 && xx >= 0 && xx < 64) v = XT[(long long)(yy*64+xx)*CIN + d];
  B2[(long long)p*(9*CIN) + r] = v;
}

// =============== transposes ===============
__global__ void k_transpose(const float* __restrict__ in, float* __restrict__ out,
                            int rows, int cols, long long instride, long long outstride){
  __shared__ float tile[32][33];
  int tx = threadIdx.x & 31, ty = threadIdx.x >> 5;
  long long c0 = (long long)blockIdx.x*32, r0 = (long long)blockIdx.y*32;
  #pragma unroll
  for (int i=0;i<32;i+=8){
    long long r = r0 + ty + i, c = c0 + tx;
    if (r < rows && c < cols) tile[ty+i][tx] = in[r*instride + c];
  }
  __syncthreads();
  #pragma unroll
  for (int i=0;i<32;i+=8){
    long long r = r0 + tx, c = c0 + ty + i;
    if (r < rows && c < cols) out[c*outstride + r] = tile[tx][ty+i];
  }
}

__global__ void k_transpose_dual(const float* __restrict__ in, float* __restrict__ outF,
                                 unsigned short* __restrict__ outB,
                                 int rows, int cols, long long instride, long long outstride){
  __shared__ float tile[32][33];
  int tx = threadIdx.x & 31, ty = threadIdx.x >> 5;
  long long c0 = (long long)blockIdx.x*32, r0 = (long long)blockIdx.y*32;
  #pragma unroll
  for (int i=0;i<32;i+=8){
    long long r = r0 + ty + i, c = c0 + tx;
    if (r < rows && c < cols) tile[ty+i][tx] = in[r*instride + c];
  }
  __syncthreads();
  #pragma unroll
  for (int i=0;i<32;i+=8){
    long long r = r0 + tx, c = c0 + ty + i;
    if (r < rows && c < cols){
      float v = tile[tx][ty+i];
      if (outF) outF[c*outstride + r] = v;
      outB[c*outstride + r] = f2bf(v);
    }
  }
}

// =============== bf16 MFMA GEMM ===============
template<int MODE>
__global__ __launch_bounds__(256)
void k_gemm_bt(const unsigned short* __restrict__ A, const unsigned short* __restrict__ B,
               int K, int N, float* __restrict__ Cout, const float* __restrict__ bias,
               const float* __restrict__ res, const unsigned int* flagp, void* dout){
  constexpr int LDK = 72;
  __shared__ unsigned short As[128*LDK], Bs[128*LDK];
  int m0 = blockIdx.x*128, n0 = blockIdx.y*128;
  int tid = threadIdx.x;
  int wave = tid >> 6, lane = tid & 63, quad = lane >> 4, l16 = lane & 15;
  int wm = wave >> 1, wn = wave & 1;
  f32x4 acc[4][4];
  #pragma unroll
  for (int a=0;a<4;++a)
    #pragma unroll
    for (int b=0;b<4;++b) acc[a][b] = (f32x4){0.f,0.f,0.f,0.f};
  int srow = tid >> 1, shalf = (tid & 1)*32;
  for (int kt = 0; kt < K; kt += 64){
    const u16x8* ga = (const u16x8*)(A + (long long)(m0+srow)*K + kt + shalf);
    const u16x8* gb = (const u16x8*)(B + (long long)(n0+srow)*K + kt + shalf);
    u16x8* da = (u16x8*)&As[srow*LDK + shalf];
    u16x8* db = (u16x8*)&Bs[srow*LDK + shalf];
    #pragma unroll
    for (int c=0;c<4;++c){ da[c] = ga[c]; db[c] = gb[c]; }
    __syncthreads();
    #pragma unroll
    for (int ks=0; ks<64; ks+=32){
      bf16x8 af[4], bfr[4];
      #pragma unroll
      for (int mi=0;mi<4;++mi)
        af[mi] = *(const bf16x8*)&As[(wm*64 + mi*16 + l16)*LDK + ks + quad*8];
      #pragma unroll
      for (int ni=0;ni<4;++ni)
        bfr[ni] = *(const bf16x8*)&Bs[(wn*64 + ni*16 + l16)*LDK + ks + quad*8];
      #pragma unroll
      for (int mi=0;mi<4;++mi)
        #pragma unroll
        for (int ni=0;ni<4;++ni)
          acc[mi][ni] = __builtin_amdgcn_mfma_f32_16x16x32_bf16(af[mi], bfr[ni], acc[mi][ni], 0, 0, 0);
    }
    __syncthreads();
  }
  bool bf = (MODE == 2) ? ((*flagp) == 0x3F803F80u) : false;
  #pragma unroll
  for (int mi=0;mi<4;++mi){
    #pragma unroll
    for (int ni=0;ni<4;++ni){
      #pragma unroll
      for (int r=0;r<4;++r){
        int m = m0 + wm*64 + mi*16 + quad*4 + r;
        int n = n0 + wn*64 + ni*16 + l16;
        float v = acc[mi][ni][r];
        if (MODE == 1) v += bias[m];
        if (MODE == 2){
          v += res[(long long)m*N + n];
          if (bf) ((unsigned short*)dout)[(long long)m*N + n] = f2bf(v);
          else    ((float*)dout)[(long long)m*N + n] = v;
        } else {
          Cout[(long long)m*N + n] = v;
        }
      }
    }
  }
}

// =============== chunked selective-scan (3 passes) ===============
// stage[j][slot]: dt r -> r, B n -> BOFF+n, C n -> BOFF+16+n.
// SROWS: number of leading dbl rows staged (p1: R+16, p3: R+32).
// u-prefetch: 8 independent global loads per group to hide L2 latency.
template<int DCH, int TD, int L, int LG, int T, int R, int CROWS, int STRIDE, int BOFF, int SROWS>
__global__ void k_scan_p1(float* __restrict__ W, long long o_dbl, long long o_xt,
                          long long o_p, long long o_s,
                          long long i_dtw, long long i_dtb, long long i_alog){
  constexpr int NT = DCH/TD;
  int k = blockIdx.x / NT, tile = blockIdx.x % NT;
  int c = blockIdx.y;
  int t = threadIdx.x;
  int dch = tile*TD + t;
  __shared__ __align__(16) float stage[T*STRIDE];
  const float* dbl = W + o_dbl + (long long)k*CROWS*L;
  const int Lm1 = L-1, mask = (1<<LG)-1;
  for (int idx = t; idx < SROWS*T; idx += TD){
    int row = idx / T, col = idx % T;
    int l = c*T + col;
    int cc = scan_addr(k, l, LG, Lm1);
    int slot = (row < R) ? row : (BOFF + row - R);
    stage[col*STRIDE + slot] = dbl[(long long)row*L + cc];
  }
  __syncthreads();
  float w[R], A[16], s[16];
  #pragma unroll
  for (int r=0;r<R;++r) w[r] = W[i_dtw + (long long)(k*DCH+dch)*R + r];
  float bias = W[i_dtb + k*DCH + dch];
  bool pat = true;
  #pragma unroll
  for (int n=0;n<16;++n){
    A[n] = -expf(W[i_alog + (long long)(k*DCH+dch)*16 + n]);
    pat = pat && (fabsf(A[n] + (float)(n+1)) <= 1e-3f*(float)(n+1));
    s[n] = 0.f;
  }
  const float* XT = W + o_xt;
  float dtsum = 0.f;
  for (int j0=0;j0<T;j0+=8){
    float uv[8];
    #pragma unroll
    for (int q=0;q<8;++q){
      int l = c*T + j0 + q;
      int p_ = (k&2)? (Lm1-l) : l;
      int ua = (k&1)? (((p_&mask)<<LG)|(p_>>LG)) : p_;
      uv[q] = XT[(long long)ua*DCH + dch];
    }
    #pragma unroll
    for (int q=0;q<8;++q){
      int j = j0 + q;
      float x = bias;
      if (R == 2){
        x += stage[j*STRIDE]*w[0] + stage[j*STRIDE+1]*w[1];
      } else {
        const f32x4* dp = (const f32x4*)&stage[j*STRIDE];
        #pragma unroll
        for (int r4=0; r4<R/4; ++r4){
          f32x4 v = dp[r4];
          x += v[0]*w[r4*4] + v[1]*w[r4*4+1] + v[2]*w[r4*4+2] + v[3]*w[r4*4+3];
        }
      }
      float e = __expf(x);
      float dt = (x > 15.f) ? x : __logf(1.f + e);
      dtsum += dt;
      float du = dt*uv[q];
      const f32x4* bp = (const f32x4*)&stage[j*STRIDE + BOFF];
      if (pat){
        float qq = 1.f/(1.f + e);
        float q2 = qq*qq, q4 = q2*q2;
        f32x4 f0; f0[0]=qq; f0[1]=q2; f0[2]=q2*qq; f0[3]=q4;
        f32x4 f1 = f0*q4, f2 = f1*q4, f3 = f2*q4;
        f32x4 B0 = bp[0], B1 = bp[1], B2 = bp[2], B3 = bp[3];
        #pragma unroll
        for (int i=0;i<4;++i){
          s[i]    = s[i]   *f0[i] + du*B0[i];
          s[4+i]  = s[4+i] *f1[i] + du*B1[i];
          s[8+i]  = s[8+i] *f2[i] + du*B2[i];
          s[12+i] = s[12+i]*f3[i] + du*B3[i];
        }
      } else {
        #pragma unroll
        for (int n4=0;n4<4;++n4){
          f32x4 B = bp[n4];
          #pragma unroll
          for (int i=0;i<4;++i){ int n=n4*4+i; s[n] = s[n]*__expf(dt*A[n]) + du*B[i]; }
        }
      }
    }
  }
  float* P = W + o_p; float* S = W + o_s;
  long long base = (long long)c*(4LL*DCH*16) + (long long)k*DCH*16 + (long long)dch*16;
  #pragma unroll
  for (int n=0;n<16;++n){ P[base+n] = __expf(dtsum*A[n]); S[base+n] = s[n]; }
}

template<int NSTATE, int CH>
__global__ void k_carry(float* __restrict__ W, long long o_p, long long o_s){
  int idx = blockIdx.x*256 + threadIdx.x;
  if (idx >= NSTATE) return;
  const float* P = W + o_p; float* S = W + o_s;
  float h = 0.f;
  for (int c=0;c<CH;++c){
    float p = P[(long long)c*NSTATE + idx];
    float s = S[(long long)c*NSTATE + idx];
    S[(long long)c*NSTATE + idx] = h;
    h = h*p + s;
  }
}

template<int DCH, int TD, int L, int LG, int T, int R, int CROWS, int STRIDE, int BOFF>
__global__ void k_scan_p3(float* __restrict__ W, long long o_dbl, long long o_xt,
                          long long o_s, long long o_ys,
                          long long i_dtw, long long i_dtb, long long i_alog, long long i_dd){
  constexpr int NT = DCH/TD;
  int k = blockIdx.x / NT, tile = blockIdx.x % NT;
  int c = blockIdx.y;
  int t = threadIdx.x;
  int dch = tile*TD + t;
  __shared__ __align__(16) float stage[T*STRIDE];
  const float* dbl = W + o_dbl + (long long)k*CROWS*L;
  const int Lm1 = L-1, mask = (1<<LG)-1;
  for (int idx = t; idx < CROWS*T; idx += TD){
    int row = idx / T, col = idx % T;
    int l = c*T + col;
    int cc = scan_addr(k, l, LG, Lm1);
    int slot = (row < R) ? row : (BOFF + row - R);
    stage[col*STRIDE + slot] = dbl[(long long)row*L + cc];
  }
  __syncthreads();
  float w[R], A[16], s[16];
  #pragma unroll
  for (int r=0;r<R;++r) w[r] = W[i_dtw + (long long)(k*DCH+dch)*R + r];
  float bias = W[i_dtb + k*DCH + dch];
  float Dv = W[i_dd + k*DCH + dch];
  long long sbase = (long long)c*(4LL*DCH*16) + (long long)k*DCH*16 + (long long)dch*16;
  bool pat = true;
  #pragma unroll
  for (int n=0;n<16;++n){
    A[n] = -expf(W[i_alog + (long long)(k*DCH+dch)*16 + n]);
    pat = pat && (fabsf(A[n] + (float)(n+1)) <= 1e-3f*(float)(n+1));
    s[n] = W[o_s + sbase + n];
  }
  const float* XT = W + o_xt;
  __half* Y = (__half*)(W + o_ys);
  for (int j0=0;j0<T;j0+=8){
    float uv[8];
    #pragma unroll
    for (int q=0;q<8;++q){
      int l = c*T + j0 + q;
      int p_ = (k&2)? (Lm1-l) : l;
      int ua = (k&1)? (((p_&mask)<<LG)|(p_>>LG)) : p_;
      uv[q] = XT[(long long)ua*DCH + dch];
    }
    #pragma unroll
    for (int q=0;q<8;++q){
      int j = j0 + q;
      int l = c*T + j;
      float x = bias;
      if (R == 2){
        x += stage[j*STRIDE]*w[0] + stage[j*STRIDE+1]*w[1];
      } else {
        const f32x4* dp = (const f32x4*)&stage[j*STRIDE];
        #pragma unroll
        for (int r4=0; r4<R/4; ++r4){
          f32x4 v = dp[r4];
          x += v[0]*w[r4*4] + v[1]*w[r4*4+1] + v[2]*w[r4*4+2] + v[3]*w[r4*4+3];
        }
      }
      float e = __expf(x);
      float dt = (x > 15.f) ? x : __logf(1.f + e);
      float du = dt*uv[q];
      float y = Dv*uv[q];
      const f32x4* bp = (const f32x4*)&stage[j*STRIDE + BOFF];
      const f32x4* cp = (const f32x4*)&stage[j*STRIDE + BOFF + 16];
      if (pat){
        float qq = 1.f/(1.f + e);
        float q2 = qq*qq, q4 = q2*q2;
        f32x4 f0; f0[0]=qq; f0[1]=q2; f0[2]=q2*qq; f0[3]=q4;
        f32x4 f1 = f0*q4, f2 = f1*q4, f3 = f2*q4;
        f32x4 B0 = bp[0], B1 = bp[1], B2 = bp[2], B3 = bp[3];
        f32x4 C0 = cp[0], C1 = cp[1], C2 = cp[2], C3 = cp[3];
        #pragma unroll
        for (int i=0;i<4;++i){
          s[i]    = s[i]   *f0[i] + du*B0[i];
          s[4+i]  = s[4+i] *f1[i] + du*B1[i];
          s[8+i]  = s[8+i] *f2[i] + du*B2[i];
          s[12+i] = s[12+i]*f3[i] + du*B3[i];
        }
        #pragma unroll
        for (int i=0;i<4;++i)
          y += s[i]*C0[i] + s[4+i]*C1[i] + s[8+i]*C2[i] + s[12+i]*C3[i];
      } else {
        #pragma unroll
        for (int n4=0;n4<4;++n4){
          f32x4 B = bp[n4], C = cp[n4];
          #pragma unroll
          for (int i=0;i<4;++i){
            int n = n4*4+i;
            s[n] = s[n]*__expf(dt*A[n]) + du*B[i];
            y += s[n]*C[i];
          }
        }
      }
      Y[(long long)l*(4*DCH) + k*DCH + dch] = __float2half(y);
    }
  }
}

// =============== stage A: c0 ===============
__global__ void k_c0(float* __restrict__ W){
  int i = blockIdx.x*256 + threadIdx.x; if (i >= 32*512) return;
  int c = i >> 9, l = i & 511;
  float acc = W[I_C0B + c];
  for (int ii=0; ii<18; ++ii)
    for (int j=0; j<3; ++j){
      int p = l-1+j;
      if (p >= 0 && p < 512) acc += W[I_LD + ii*512 + p] * W[I_C0W + (c*18+ii)*3 + j];
    }
  W[O_X0 + i] = acc;
}

// =============== stage B: mamba2 ===============
__global__ void k_zxf(float* __restrict__ W){
  int j = blockIdx.x;
  int t = threadIdx.x, l = t & 31, kc = t >> 5;
  __shared__ float wrow[512];
  for (int idx = t; idx < 512; idx += 256) wrow[idx] = W[I_MINW + (long long)j*512 + idx];
  __syncthreads();
  float acc = 0.f;
  const float* u = W + O_X0 + l*512;
  for (int d = kc*64; d < kc*64 + 64; ++d) acc += u[d]*wrow[d];
  __shared__ float red[256];
  red[t] = acc; __syncthreads();
  if (kc == 0){
    float s = 0.f;
    #pragma unroll
    for (int q=0;q<8;++q) s += red[l + q*32];
    W[O_ZX + l*2320 + j] = s;
  }
}

__global__ void k_conv4(float* __restrict__ W){
  int i = blockIdx.x*256 + threadIdx.x; if (i >= 32*1280) return;
  int l = i / 1280, c = i % 1280;
  float acc = W[I_MCONVB + c];
  for (int j=0; j<4; ++j){
    int p = l-3+j;
    if (p >= 0) acc += W[O_ZX + p*2320 + 1024 + c] * W[I_MCONVW + c*4 + j];
  }
  W[O_XBCC + l*1280 + c] = siluf(acc);
}

__global__ void k_dtm(float* __restrict__ W){
  int i = blockIdx.x*256 + threadIdx.x; if (i >= 512) return;
  int l = i >> 4, h = i & 15;
  W[O_DTM + i] = softplusf(W[O_ZX + l*2320 + 2304 + h] + W[I_MDTB + h]);
}

__global__ void k_mscan(float* __restrict__ W){
  int h = blockIdx.x >> 6, pp = blockIdx.x & 63;
  int lane = threadIdx.x;
  float A = -expf(W[I_MALOG + h]);
  float Dv = W[I_MD + h];
  float s0 = 0.f, s1 = 0.f;
  for (int l=0; l<32; ++l){
    float dt = W[O_DTM + l*16 + h];
    float xv = W[O_XBCC + l*1280 + h*64 + pp];
    float dA = expf(dt*A);
    float b0 = W[O_XBCC + l*1280 + 1024 + lane];
    float b1 = W[O_XBCC + l*1280 + 1088 + lane];
    float c0 = W[O_XBCC + l*1280 + 1152 + lane];
    float c1 = W[O_XBCC + l*1280 + 1216 + lane];
    float du = dt*xv;
    s0 = s0*dA + du*b0;
    s1 = s1*dA + du*b1;
    float part = s0*c0 + s1*c1;
    for (int off=32; off; off>>=1) part += __shfl_xor(part, off, 64);
    if (lane == 0) W[O_TPRE + l*1024 + h*64 + pp] = part + Dv*xv;
  }
}

__global__ void k_gaterms(float* __restrict__ W){
  int l = blockIdx.x, t = threadIdx.x;
  float vals[4]; float ss = 0.f;
  for (int q=0; q<4; ++q){
    int c = t + q*256;
    float z = W[O_ZX + l*2320 + c];
    float y = W[O_TPRE + l*1024 + c];
    float v = y * siluf(z);
    vals[q] = v; ss += v*v;
  }
  for (int off=32; off; off>>=1) ss += __shfl_xor(ss, off, 64);
  __shared__ float sm[4];
  if ((t & 63) == 0) sm[t>>6] = ss;
  __syncthreads();
  float tot = sm[0]+sm[1]+sm[2]+sm[3];
  float r = rsqrtf(tot/1024.f + 1e-5f);
  for (int q=0; q<4; ++q){
    int c = t + q*256;
    W[O_TG + l*1024 + c] = vals[q]*r*W[I_MNORMW + c];
  }
}

__global__ void k_outmf(float* __restrict__ W){
  int d = blockIdx.x;
  int t = threadIdx.x, l = t & 31, kc = t >> 5;
  __shared__ float wrow[1024];
  for (int idx = t; idx < 1024; idx += 256) wrow[idx] = W[I_MOUTW + (long long)d*1024 + idx];
  __syncthreads();
  float acc = 0.f;
  const float* tg = W + O_TG + l*1024;
  for (int c = kc*128; c < kc*128 + 128; ++c) acc += tg[c]*wrow[c];
  __shared__ float red[256];
  red[t] = acc; __syncthreads();
  if (kc == 0){
    float s = 0.f;
    #pragma unroll
    for (int q=0;q<8;++q) s += red[l + q*32];
    W[O_OUTM + l*512 + d] = s;
  }
}

// =============== stage C: c1 ===============
__global__ void k_c1f(float* __restrict__ W){
  int o = blockIdx.x;
  int t = threadIdx.x, l = t & 31, kc = t >> 5;
  __shared__ float wrow[1536];
  for (int idx = t; idx < 1536; idx += 256) wrow[idx] = W[I_C1W + (long long)o*1536 + idx];
  __syncthreads();
  float acc = 0.f;
  for (int ii = kc*64; ii < kc*64 + 64; ++ii){
    #pragma unroll
    for (int j=0;j<3;++j){
      int p = l-1+j;
      if (p >= 0 && p < 32) acc += W[O_OUTM + p*512 + ii] * wrow[ii*3+j];
    }
  }
  __shared__ float red[256];
  red[t] = acc; __syncthreads();
  if (kc == 0){
    float s = W[I_C1B + o];
    #pragma unroll
    for (int q=0;q<8;++q) s += red[l + q*32];
    W[O_Y1 + o*32 + l] = s;
  }
}

// =============== vssblock 1 ===============
__global__ void k_ln1(float* __restrict__ W){
  int l = blockIdx.x*256 + threadIdx.x; if (l >= 1024) return;
  float s = 0.f, s2 = 0.f;
  for (int c=0; c<32; ++c){ float v = W[O_Y1 + l*32 + c]; s += v; s2 += v*v; }
  float mu = s/32.f, var = s2/32.f - mu*mu, rs = rsqrtf(var + 1e-5f);
  for (int c=0; c<32; ++c){
    float v = W[O_Y1 + l*32 + c];
    W[O_H1 + l*32 + c] = (v-mu)*rs*W[I_V1LNW + c] + W[I_V1LNB + c];
  }
}

__global__ void k_xz1(float* __restrict__ W){
  int i = blockIdx.x*256 + threadIdx.x; if (i >= 1024*128) return;
  int l = i >> 7, j = i & 127;
  float acc = 0.f;
  for (int c=0; c<32; ++c) acc += W[O_H1 + l*32 + c] * W[I_V1INW + j*32 + c];
  W[O_XZ1 + i] = acc;
}

__global__ void k_dwcs1(float* __restrict__ W){
  int i = blockIdx.x*256 + threadIdx.x; if (i >= 64*1024) return;
  int ch = i >> 10, pix = i & 1023, a = pix >> 5, b = pix & 31;
  float acc = W[I_V1CONVB + ch];
  for (int dy=0; dy<3; ++dy){
    int aa = a+dy-1; if (aa < 0 || aa > 31) continue;
    for (int dx=0; dx<3; ++dx){
      int bb = b+dx-1; if (bb < 0 || bb > 31) continue;
      acc += W[O_XZ1 + (aa*32+bb)*128 + ch] * W[I_V1CONVW + ch*9 + dy*3 + dx];
    }
  }
  W[O_XC1 + i] = siluf(acc);
}

__global__ void k_dbl1(float* __restrict__ W){
  int i = blockIdx.x*256 + threadIdx.x; if (i >= 4*34*1024) return;
  int k = i / 34816, r = i % 34816, c = r / 1024, l = r % 1024;
  float acc = 0.f;
  for (int d=0; d<64; ++d) acc += W[O_XC1 + d*1024 + l] * W[I_V1XPW + (k*34+c)*64 + d];
  W[O_DBL1 + (k*34+c)*1024 + l] = acc;
}

__global__ void k_comb1(float* __restrict__ W){
  int l = blockIdx.x, dch = threadIdx.x;
  int t1 = ((l & 31) << 5) | (l >> 5);
  const __half* Y = (const __half*)(W + O_YS1);
  float x = __half2float(Y[l*256 + dch])
          + __half2float(Y[t1*256 + 64 + dch])
          + __half2float(Y[(1023-l)*256 + 128 + dch])
          + __half2float(Y[(1023-t1)*256 + 192 + dch]);
  float s = x, s2 = x*x;
  for (int off=32; off; off>>=1){ s += __shfl_xor(s, off, 64); s2 += __shfl_xor(s2, off, 64); }
  float mu = s/64.f, var = s2/64.f - mu*mu, rs = rsqrtf(var + 1e-5f);
  float yn = (x-mu)*rs*W[I_V1ONW + dch] + W[I_V1ONB + dch];
  float z = W[O_XZ1 + l*128 + 64 + dch];
  W[O_G1 + l*64 + dch] = yn * siluf(z);
}

__global__ void k_oproj1(float* __restrict__ W){
  int i = blockIdx.x*256 + threadIdx.x; if (i >= 1024*32) return;
  int l = i >> 5, c = i & 31;
  float acc = W[O_Y1 + i];
  for (int d=0; d<64; ++d) acc += W[O_G1 + l*64 + d] * W[I_V1OUTW + c*64 + d];
  W[O_OUTD + i] = acc;
}

// =============== stage E: conv stack ===============
__global__ void k_dw1(float* __restrict__ W){
  int i = blockIdx.x*256 + threadIdx.x; if (i >= 32*1024) return;
  int c = i >> 10, pix = i & 1023, a = pix >> 5, b = pix & 31;
  float acc = W[I_DW1B + c];
  for (int dy=0; dy<3; ++dy){
    int aa = a+dy-1; if (aa < 0 || aa > 31) continue;
    for (int dx=0; dx<3; ++dx){
      int bb = b+dx-1; if (bb < 0 || bb > 31) continue;
      acc += W[O_OUTD + (aa*32+bb)*32 + c] * W[I_DW1W + c*9 + dy*3 + dx];
    }
  }
  W[O_E1 + i] = acc;
}

__global__ void k_pw1(float* __restrict__ W){
  int i = blockIdx.x*256 + threadIdx.x; if (i >= 64*1024) return;
  int o = i >> 10, pix = i & 1023;
  float acc = W[I_PW1B + o];
  for (int c=0; c<32; ++c) acc += W[I_PW1W + o*32 + c] * W[O_E1 + c*1024 + pix];
  W[O_E2 + i] = acc;
}

__global__ void k_dw2(float* __restrict__ W){
  int i = blockIdx.x*256 + threadIdx.x; if (i >= 64*1024) return;
  int c = i >> 10, pix = i & 1023, a = pix >> 5, b = pix & 31;
  float acc = W[I_DW2B + c];
  for (int dy=0; dy<3; ++dy){
    int aa = a+dy-1; if (aa < 0 || aa > 31) continue;
    for (int dx=0; dx<3; ++dx){
      int bb = b+dx-1; if (bb < 0 || bb > 31) continue;
      acc += W[O_E2 + c*1024 + aa*32 + bb] * W[I_DW2W + c*9 + dy*3 + dx];
    }
  }
  W[O_E3 + i] = acc;
}

__global__ void k_pw2(float* __restrict__ W){
  int i = blockIdx.x*256 + threadIdx.x; if (i >= 128*1024) return;
  int o = i >> 10, pix = i & 1023;
  float acc = W[I_PW2B + o];
  for (int c=0; c<64; ++c) acc += W[I_PW2W + o*64 + c] * W[O_E3 + c*1024 + pix];
  W[O_E4 + i] = acc;
}

DEV void rs_coef(int o, int n, int& i0, int& i1, float& w0, float& w1){
  float src = 0.5f*(float)o - 0.25f;
  float f = floorf(src);
  float fr = src - f;
  int a = (int)f;
  if (a < 0){ i0 = 0; i1 = 0; w0 = 0.f; w1 = 1.f; }
  else if (a >= n-1){ i0 = n-1; i1 = n-1; w0 = 1.f; w1 = 0.f; }
  else { i0 = a; i1 = a+1; w0 = 1.f-fr; w1 = fr; }
}

__global__ void k_resize(float* __restrict__ W){
  int i = blockIdx.x*256 + threadIdx.x; if (i >= 128*4096) return;
  int c = i >> 12, pix = i & 4095, y = pix >> 6, x = pix & 63;
  int iy0, iy1, ix0, ix1; float wy0, wy1, wx0, wx1;
  rs_coef(y, 32, iy0, iy1, wy0, wy1);
  rs_coef(x, 32, ix0, ix1, wx0, wx1);
  const float* in = W + O_E4 + c*1024;
  float v = wy0*(wx0*in[iy0*32+ix0] + wx1*in[iy0*32+ix1])
          + wy1*(wx0*in[iy1*32+ix0] + wx1*in[iy1*32+ix1]);
  W[O_E5 + i] = v;
}

// =============== stage F: vssblock2 ===============
__global__ void k_ln2(float* __restrict__ W){
  int l = blockIdx.x, t = threadIdx.x;
  float v0 = W[O_E8 + (long long)t*4096 + l];
  float v1 = W[O_E8 + (long long)(t+256)*4096 + l];
  float s = v0+v1, s2 = v0*v0 + v1*v1;
  for (int off=32; off; off>>=1){ s += __shfl_xor(s, off, 64); s2 += __shfl_xor(s2, off, 64); }
  __shared__ float a[4], b[4];
  if ((t & 63) == 0){ a[t>>6] = s; b[t>>6] = s2; }
  __syncthreads();
  float S = a[0]+a[1]+a[2]+a[3], S2 = b[0]+b[1]+b[2]+b[3];
  float mu = S/512.f, var = S2/512.f - mu*mu, rs = rsqrtf(var + 1e-5f);
  unsigned short* H = (unsigned short*)(W + O_LN2);
  H[(long long)l*512 + t]     = f2bf((v0-mu)*rs*W[I_V2LNW + t]     + W[I_V2LNB + t]);
  H[(long long)l*512 + t+256] = f2bf((v1-mu)*rs*W[I_V2LNW + t+256] + W[I_V2LNB + t+256]);
}

__global__ void k_dwcs2(float* __restrict__ W){
  long long i = (long long)blockIdx.x*256 + threadIdx.x;
  int ch = (int)(i >> 12), pix = (int)(i & 4095), a = pix >> 6, b = pix & 63;
  float acc = W[I_V2CONVB + ch];
  const float* xp = W + O_XT2 + (long long)ch*4096;
  for (int dy=0; dy<3; ++dy){
    int aa = a+dy-1; if (aa < 0 || aa > 63) continue;
    for (int dx=0; dx<3; ++dx){
      int bb = b+dx-1; if (bb < 0 || bb > 63) continue;
      acc += xp[aa*64+bb] * W[I_V2CONVW + ch*9 + dy*3 + dx];
    }
  }
  W[O_XC2 + i] = siluf(acc);
}

__global__ void k_comb2(float* __restrict__ W){
  int l = blockIdx.x, t = threadIdx.x;
  int t1 = ((l & 63) << 6) | (l >> 6);
  const __half* Y = (const __half*)(W + O_YS2);
  float v[4]; float s = 0.f, s2 = 0.f;
  for (int q=0; q<4; ++q){
    int dch = t + q*256;
    float x = __half2float(Y[(long long)l*4096 + dch])
            + __half2float(Y[(long long)t1*4096 + 1024 + dch])
            + __half2float(Y[(long long)(4095-l)*4096 + 2048 + dch])
            + __half2float(Y[(long long)(4095-t1)*4096 + 3072 + dch]);
    v[q] = x; s += x; s2 += x*x;
  }
  for (int off=32; off; off>>=1){ s += __shfl_xor(s, off, 64); s2 += __shfl_xor(s2, off, 64); }
  __shared__ float a[4], b[4];
  if ((t & 63) == 0){ a[t>>6] = s; b[t>>6] = s2; }
  __syncthreads();
  float S = a[0]+a[1]+a[2]+a[3], S2 = b[0]+b[1]+b[2]+b[3];
  float mu = S/1024.f, var = S2/1024.f - mu*mu, rs = rsqrtf(var + 1e-5f);
  unsigned short* G = (unsigned short*)(W + O_G2);
  for (int q=0; q<4; ++q){
    int dch = t + q*256;
    float yn = (v[q]-mu)*rs*W[I_V2ONW + dch] + W[I_V2ONB + dch];
    float z = W[O_XZ2 + (long long)l*2048 + 1024 + dch];
    G[(long long)l*1024 + dch] = f2bf(yn * siluf(z));
  }
}

// =============== launch ===============
extern "C" void kernel_launch(void* const* d_in, const int* in_sizes, int n_in,
                              void* d_out, int out_size, void* d_ws, size_t ws_size,
                              hipStream_t stream){
  if (ws_size < (size_t)WS_FLOATS * sizeof(float)) return;
  float* W = (float*)d_ws;
  PtrTab tab;
  for (int i=0; i<53; ++i) tab.p[i] = d_in[i];
  const unsigned int* flagp = (const unsigned int*)d_in[9];

  k_ingest<<<INGEST_BLOCKS, 256, 0, stream>>>(tab, W);
  k_prep  <<<12480, 256, 0, stream>>>(W);

  k_c0    <<<64, 256, 0, stream>>>(W);
  k_zxf   <<<2320, 256, 0, stream>>>(W);
  k_conv4 <<<160, 256, 0, stream>>>(W);
  k_dtm   <<<2, 256, 0, stream>>>(W);
  k_mscan <<<1024, 64, 0, stream>>>(W);
  k_gaterms<<<32, 256, 0, stream>>>(W);
  k_outmf <<<512, 256, 0, stream>>>(W);
  k_c1f   <<<1024, 256, 0, stream>>>(W);
  k_ln1   <<<4, 256, 0, stream>>>(W);
  k_xz1   <<<512, 256, 0, stream>>>(W);
  k_dwcs1 <<<256, 256, 0, stream>>>(W);
  k_dbl1  <<<544, 256, 0, stream>>>(W);
  // vss1 chunked scan
  k_transpose<<<dim3(32, 2), 256, 0, stream>>>(W + O_XC1, W + O_XT1, 64, 1024, 1024, 64);
  k_scan_p1<64,64,1024,5,64,2,34,40,4,18><<<dim3(4,16), 64, 0, stream>>>(W, O_DBL1, O_XT1, O_P1, O_S1,
                                                                 I_V1DTW, I_V1DTB, I_V1ALOG);
  k_carry<4096,16><<<16, 256, 0, stream>>>(W, O_P1, O_S1);
  k_scan_p3<64,64,1024,5,64,2,34,40,4><<<dim3(4,16), 64, 0, stream>>>(W, O_DBL1, O_XT1, O_S1, O_YS1,
                                                                 I_V1DTW, I_V1DTB, I_V1ALOG, I_V1D);
  k_comb1 <<<1024, 64, 0, stream>>>(W);
  k_oproj1<<<128, 256, 0, stream>>>(W);
  k_dw1   <<<128, 256, 0, stream>>>(W);
  k_pw1   <<<256, 256, 0, stream>>>(W);
  k_dw2   <<<256, 256, 0, stream>>>(W);
  k_pw2   <<<512, 256, 0, stream>>>(W);
  k_resize<<<2048, 256, 0, stream>>>(W);
  // cv1 via MFMA
  k_transpose_dual<<<dim3(128, 4), 256, 0, stream>>>(W + O_E5, nullptr,
                      (unsigned short*)(W + O_E5TB), 128, 4096, 4096, 128);
  k_im2colT<128><<<dim3(5, 4096), 256, 0, stream>>>((const unsigned short*)(W + O_E5TB),
                      (unsigned short*)(W + O_CV1B2));
  k_gemm_bt<1><<<dim3(1, 32), 256, 0, stream>>>((const unsigned short*)(W + O_CV1WB),
                      (const unsigned short*)(W + O_CV1B2), 1152, 4096,
                      W + O_E6, W + I_CV1B, nullptr, nullptr, nullptr);
  // cv2 via MFMA
  k_transpose_dual<<<dim3(128, 4), 256, 0, stream>>>(W + O_E6, nullptr,
                      (unsigned short*)(W + O_E6TB), 128, 4096, 4096, 128);
  k_gemm_bt<1><<<dim3(2, 32), 256, 0, stream>>>((const unsigned short*)(W + O_CV2WB),
                      (const unsigned short*)(W + O_E6TB), 128, 4096,
                      W + O_E7, W + I_CV2B, nullptr, nullptr, nullptr);
  // fc via MFMA
  k_transpose_dual<<<dim3(128, 8), 256, 0, stream>>>(W + O_E7, nullptr,
                      (unsigned short*)(W + O_E7T), 256, 4096, 4096, 256);
  k_im2colT<256><<<dim3(9, 4096), 256, 0, stream>>>((const unsigned short*)(W + O_E7T),
                      (unsigned short*)(W + O_B2));
  k_gemm_bt<1><<<dim3(4, 32), 256, 0, stream>>>((const unsigned short*)(W + O_FCW2),
                      (const unsigned short*)(W + O_B2), 2304, 4096,
                      W + O_E8, W + I_FCB, nullptr, nullptr, nullptr);
  // vss2
  k_ln2   <<<4096, 256, 0, stream>>>(W);
  k_gemm_bt<0><<<dim3(32, 16), 256, 0, stream>>>((const unsigned short*)(W + O_LN2),
                      (const unsigned short*)(W + O_W2INB), 512, 2048,
                      W + O_XZ2, nullptr, nullptr, nullptr, nullptr);
  k_transpose<<<dim3(32, 128), 256, 0, stream>>>(W + O_XZ2, W + O_XT2, 4096, 1024, 2048, 4096);
  k_dwcs2 <<<16384, 256, 0, stream>>>(W);
  k_transpose_dual<<<dim3(128, 32), 256, 0, stream>>>(W + O_XC2, W + O_XT2,
                      (unsigned short*)(W + O_XT2B), 1024, 4096, 4096, 1024);
  k_gemm_bt<0><<<dim3(2, 32), 256, 0, stream>>>((const unsigned short*)(W + O_XPWB),
                      (const unsigned short*)(W + O_XT2B), 1024, 4096,
                      W + O_DBL2, nullptr, nullptr, nullptr, nullptr);
  k_scan_p1<1024,256,4096,6,64,32,64,68,32,48><<<dim3(16,64), 256, 0, stream>>>(W, O_DBL2, O_XT2, O_P2, O_S2,
                                                                       I_V2DTW, I_V2DTB, I_V2ALOG);
  k_carry<65536,64><<<256, 256, 0, stream>>>(W, O_P2, O_S2);
  k_scan_p3<1024,256,4096,6,64,32,64,68,32><<<dim3(16,64), 256, 0, stream>>>(W, O_DBL2, O_XT2, O_S2, O_YS2,
                                                                       I_V2DTW, I_V2DTB, I_V2ALOG, I_V2D);
  k_comb2 <<<4096, 256, 0, stream>>>(W);
  k_gemm_bt<2><<<dim3(4, 32), 256, 0, stream>>>((const unsigned short*)(W + O_OUTWB),
                      (const unsigned short*)(W + O_G2), 1024, 4096,
                      nullptr, nullptr, W + O_E8, flagp, d_out);
}